// Round 1
// baseline (351.757 us; speedup 1.0000x reference)
//
#include <hip/hip_runtime.h>
#include <math.h>

#define S_ 2048
#define E_ 2048
#define H_ 16
#define D_ 128

typedef _Float16 f16;
typedef _Float16 f16x8 __attribute__((ext_vector_type(8)));
typedef _Float16 f16x4 __attribute__((ext_vector_type(4)));
typedef float f32x4 __attribute__((ext_vector_type(4)));

// ---------------------------------------------------------------- convert
__global__ __launch_bounds__(256) void cvt_f32_f16(const float* __restrict__ in,
                                                   f16* __restrict__ out, int n) {
    int i = (blockIdx.x * 256 + threadIdx.x) * 4;
    if (i + 3 < n) {
        float4 v = *(const float4*)(in + i);
        f16x4 o;
        o[0] = (f16)v.x; o[1] = (f16)v.y; o[2] = (f16)v.z; o[3] = (f16)v.w;
        *(f16x4*)(out + i) = o;
    }
}

// ---------------------------------------------------------------- QKV GEMM
// C[m][n] = sum_k A[m][k] * B[n][k] + bias[n]   (NT, both row-major, K inner)
// M=2048 (s), N=6144 (3E), K=2048. Epilogue scatters into Q/K (f16 [H][S][D])
// and V transposed (f16 [H][D][S]).
__global__ __launch_bounds__(256) void gemm_qkv(const f16* __restrict__ A,
                                                const f16* __restrict__ B,
                                                const float* __restrict__ bias,
                                                f16* __restrict__ Qm,
                                                f16* __restrict__ Km,
                                                f16* __restrict__ VTm) {
    __shared__ __align__(16) f16 As[128 * 40];  // BK=32, pad to 40 (conflict-free b128)
    __shared__ __align__(16) f16 Bs[128 * 40];
    const int tid  = threadIdx.x;
    const int lane = tid & 63, wave = tid >> 6;
    const int lm = lane & 15, quad = lane >> 4;
    const int wm = wave >> 1, wn = wave & 1;
    const int tn0 = blockIdx.x * 128;
    const int tm0 = blockIdx.y * 128;

    const f32x4 vzero = {0.f, 0.f, 0.f, 0.f};
    f32x4 acc[4][4];
#pragma unroll
    for (int i = 0; i < 4; i++)
#pragma unroll
        for (int j = 0; j < 4; j++) acc[i][j] = vzero;

    for (int k0 = 0; k0 < E_; k0 += 32) {
        __syncthreads();
#pragma unroll
        for (int r = 0; r < 2; r++) {
            int c = r * 256 + tid;      // 512 chunks of 16B per tile
            int row = c >> 2, cc = c & 3;
            *(float4*)(As + row * 40 + cc * 8) =
                *(const float4*)(A + (size_t)(tm0 + row) * E_ + k0 + cc * 8);
            *(float4*)(Bs + row * 40 + cc * 8) =
                *(const float4*)(B + (size_t)(tn0 + row) * E_ + k0 + cc * 8);
        }
        __syncthreads();
        f16x8 af[4], bfr[4];
#pragma unroll
        for (int i = 0; i < 4; i++)
            af[i] = *(const f16x8*)(As + (wm * 64 + i * 16 + lm) * 40 + quad * 8);
#pragma unroll
        for (int j = 0; j < 4; j++)
            bfr[j] = *(const f16x8*)(Bs + (wn * 64 + j * 16 + lm) * 40 + quad * 8);
#pragma unroll
        for (int i = 0; i < 4; i++)
#pragma unroll
            for (int j = 0; j < 4; j++)
                acc[i][j] = __builtin_amdgcn_mfma_f32_16x16x32_f16(af[i], bfr[j],
                                                                   acc[i][j], 0, 0, 0);
    }

#pragma unroll
    for (int i = 0; i < 4; i++) {
#pragma unroll
        for (int j = 0; j < 4; j++) {
            const int n = tn0 + wn * 64 + j * 16 + lm;
            const int which = n >> 11;          // 0=q 1=k 2=v
            const int h = (n >> 7) & 15;
            const int d = n & 127;
            const float bv = bias[n];
#pragma unroll
            for (int r = 0; r < 4; r++) {
                const int m = tm0 + wm * 64 + i * 16 + quad * 4 + r;  // s index
                f16 v = (f16)(acc[i][j][r] + bv);
                if (which == 0)      Qm[((size_t)h * S_ + m) * D_ + d] = v;
                else if (which == 1) Km[((size_t)h * S_ + m) * D_ + d] = v;
                else                 VTm[((size_t)h * D_ + d) * S_ + m] = v;
            }
        }
    }
}

// ---------------------------------------------------------------- attention
// Flash-style causal MHA. Block = 4 waves; q-tile 64 (16 rows/wave); kv-tile 64.
// C/D layout: col=lane&15, row=quad*4+reg (m89/m91). A layout: m=lane&15,
// k=quad*8+j (m120). P round-trips C-layout -> LDS -> A-layout.
__global__ __launch_bounds__(256) void attn(const f16* __restrict__ Qm,
                                            const f16* __restrict__ Km,
                                            const f16* __restrict__ VTm,
                                            f16* __restrict__ Om) {
    __shared__ __align__(16) f16 Ks[64 * 128];    // [k_local][d]
    __shared__ __align__(16) f16 VTs[128 * 64];   // [d][k_local]
    __shared__ __align__(16) f16 Ps[4][16 * 64];  // per-wave P scratch

    const int tid  = threadIdx.x;
    const int lane = tid & 63, wave = tid >> 6;
    const int lm = lane & 15, quad = lane >> 4;
    const int bx = blockIdx.x;
    const int qt = 31 - (bx >> 4);   // heavy (large-qt) blocks dispatch first
    const int h  = bx & 15;
    const int q0 = qt * 64;

    // Q fragments for this wave's 16 rows (held for whole kernel)
    const int qrow = q0 + wave * 16 + lm;
    const f16* qbase = Qm + ((size_t)h * S_ + qrow) * D_;
    f16x8 qf[4];
#pragma unroll
    for (int kc = 0; kc < 4; kc++)
        qf[kc] = *(const f16x8*)(qbase + kc * 32 + quad * 8);

    const f32x4 vzero = {0.f, 0.f, 0.f, 0.f};
    f32x4 o[8];
#pragma unroll
    for (int f = 0; f < 8; f++) o[f] = vzero;
    float m_i[4], l_i[4];
#pragma unroll
    for (int r = 0; r < 4; r++) { m_i[r] = -INFINITY; l_i[r] = 0.f; }

    const float scale = 0.08838834764831845f;  // 1/sqrt(128)

    for (int t = 0; t <= qt; t++) {
        const int k0 = t * 64;
        __syncthreads();
#pragma unroll
        for (int rr = 0; rr < 4; rr++) {
            int c = rr * 256 + tid;
            int row = c >> 4, cc = c & 15;    // Ks: 64 rows x 16 chunks
            *(float4*)(Ks + row * 128 + cc * 8) =
                *(const float4*)(Km + ((size_t)h * S_ + k0 + row) * D_ + cc * 8);
            int dd = c >> 3, c2 = c & 7;      // VTs: 128 rows x 8 chunks
            *(float4*)(VTs + dd * 64 + c2 * 8) =
                *(const float4*)(VTm + ((size_t)h * D_ + dd) * S_ + k0 + c2 * 8);
        }
        __syncthreads();

        // S = Q K^T  (16 q-rows x 64 keys, 4 col-frags)
        f32x4 sfr[4];
#pragma unroll
        for (int j = 0; j < 4; j++) {
            f32x4 a = vzero;
#pragma unroll
            for (int kc = 0; kc < 4; kc++) {
                f16x8 kf = *(const f16x8*)(Ks + (j * 16 + lm) * 128 + kc * 32 + quad * 8);
                a = __builtin_amdgcn_mfma_f32_16x16x32_f16(qf[kc], kf, a, 0, 0, 0);
            }
            sfr[j] = a;
        }

        // online softmax per q-row (rows quad*4+r in this lane)
#pragma unroll
        for (int r = 0; r < 4; r++) {
            const int qr = q0 + wave * 16 + quad * 4 + r;
            float sv[4];
            float vmax = -1e30f;
#pragma unroll
            for (int j = 0; j < 4; j++) {
                float x = sfr[j][r] * scale;
                int key = k0 + j * 16 + lm;
                sv[j] = (key > qr) ? -1e30f : x;  // == ref's -10000: exp underflows to 0
                vmax = fmaxf(vmax, sv[j]);
            }
#pragma unroll
            for (int off = 1; off < 16; off <<= 1)
                vmax = fmaxf(vmax, __shfl_xor(vmax, off));
            float mn = fmaxf(m_i[r], vmax);
            float alpha = __expf(m_i[r] - mn);    // first tile: exp(-inf)=0
            m_i[r] = mn;
            float rsum = 0.f;
#pragma unroll
            for (int j = 0; j < 4; j++) {
                float pv = __expf(sv[j] - mn);
                rsum += pv;
                Ps[wave][(quad * 4 + r) * 64 + j * 16 + lm] = (f16)pv;
            }
#pragma unroll
            for (int off = 1; off < 16; off <<= 1)
                rsum += __shfl_xor(rsum, off);
            l_i[r] = alpha * l_i[r] + rsum;
#pragma unroll
            for (int f = 0; f < 8; f++) o[f][r] *= alpha;
        }

        // O += P V  (P from per-wave LDS in A-layout; VT gives contiguous B-frags)
#pragma unroll
        for (int kc = 0; kc < 2; kc++) {
            f16x8 pf = *(const f16x8*)(&Ps[wave][lm * 64 + kc * 32 + quad * 8]);
#pragma unroll
            for (int f = 0; f < 8; f++) {
                f16x8 vf = *(const f16x8*)(VTs + (f * 16 + lm) * 64 + kc * 32 + quad * 8);
                o[f] = __builtin_amdgcn_mfma_f32_16x16x32_f16(pf, vf, o[f], 0, 0, 0);
            }
        }
    }

    // epilogue: vals[s][h*128+d]
#pragma unroll
    for (int r = 0; r < 4; r++) {
        const int qr = q0 + wave * 16 + quad * 4 + r;
        const float inv = 1.f / l_i[r];
#pragma unroll
        for (int f = 0; f < 8; f++)
            Om[(size_t)qr * E_ + h * 128 + f * 16 + lm] = (f16)(o[f][r] * inv);
    }
}

// ---------------------------------------------------------------- out GEMM
// out[m][n] = sum_k vals[m][k] * w_out[n][k] + b_out[n], fp32 output
__global__ __launch_bounds__(256) void gemm_out(const f16* __restrict__ A,
                                                const f16* __restrict__ B,
                                                const float* __restrict__ bias,
                                                float* __restrict__ Cout) {
    __shared__ __align__(16) f16 As[128 * 40];
    __shared__ __align__(16) f16 Bs[128 * 40];
    const int tid  = threadIdx.x;
    const int lane = tid & 63, wave = tid >> 6;
    const int lm = lane & 15, quad = lane >> 4;
    const int wm = wave >> 1, wn = wave & 1;
    const int tn0 = blockIdx.x * 128;
    const int tm0 = blockIdx.y * 128;

    const f32x4 vzero = {0.f, 0.f, 0.f, 0.f};
    f32x4 acc[4][4];
#pragma unroll
    for (int i = 0; i < 4; i++)
#pragma unroll
        for (int j = 0; j < 4; j++) acc[i][j] = vzero;

    for (int k0 = 0; k0 < E_; k0 += 32) {
        __syncthreads();
#pragma unroll
        for (int r = 0; r < 2; r++) {
            int c = r * 256 + tid;
            int row = c >> 2, cc = c & 3;
            *(float4*)(As + row * 40 + cc * 8) =
                *(const float4*)(A + (size_t)(tm0 + row) * E_ + k0 + cc * 8);
            *(float4*)(Bs + row * 40 + cc * 8) =
                *(const float4*)(B + (size_t)(tn0 + row) * E_ + k0 + cc * 8);
        }
        __syncthreads();
        f16x8 af[4], bfr[4];
#pragma unroll
        for (int i = 0; i < 4; i++)
            af[i] = *(const f16x8*)(As + (wm * 64 + i * 16 + lm) * 40 + quad * 8);
#pragma unroll
        for (int j = 0; j < 4; j++)
            bfr[j] = *(const f16x8*)(Bs + (wn * 64 + j * 16 + lm) * 40 + quad * 8);
#pragma unroll
        for (int i = 0; i < 4; i++)
#pragma unroll
            for (int j = 0; j < 4; j++)
                acc[i][j] = __builtin_amdgcn_mfma_f32_16x16x32_f16(af[i], bfr[j],
                                                                   acc[i][j], 0, 0, 0);
    }

#pragma unroll
    for (int i = 0; i < 4; i++) {
#pragma unroll
        for (int j = 0; j < 4; j++) {
            const int n = tn0 + wn * 64 + j * 16 + lm;
            const float bv = bias[n];
#pragma unroll
            for (int r = 0; r < 4; r++) {
                const int m = tm0 + wm * 64 + i * 16 + quad * 4 + r;
                Cout[(size_t)m * E_ + n] = acc[i][j][r] + bv;
            }
        }
    }
}

// ---------------------------------------------------------------- launch
extern "C" void kernel_launch(void* const* d_in, const int* in_sizes, int n_in,
                              void* d_out, int out_size, void* d_ws, size_t ws_size,
                              hipStream_t stream) {
    const float* x     = (const float*)d_in[0];
    const float* w_qkv = (const float*)d_in[1];
    const float* b_qkv = (const float*)d_in[2];
    const float* w_out = (const float*)d_in[3];
    const float* b_out = (const float*)d_in[4];
    float* out = (float*)d_out;

    char* ws = (char*)d_ws;
    f16* xb  = (f16*)ws; ws += (size_t)S_ * E_ * 2;       // 8 MB
    f16* wqb = (f16*)ws; ws += (size_t)3 * E_ * E_ * 2;   // 25 MB
    f16* wob = (f16*)ws; ws += (size_t)E_ * E_ * 2;       // 8 MB
    f16* Qm  = (f16*)ws; ws += (size_t)H_ * S_ * D_ * 2;  // 8 MB
    f16* Km  = (f16*)ws; ws += (size_t)H_ * S_ * D_ * 2;  // 8 MB
    f16* VTm = (f16*)ws; ws += (size_t)H_ * D_ * S_ * 2;  // 8 MB
    f16* Om  = (f16*)ws; ws += (size_t)S_ * E_ * 2;       // 8 MB  (total ~73 MB)

    cvt_f32_f16<<<4096, 256, 0, stream>>>(x, xb, S_ * E_);
    cvt_f32_f16<<<12288, 256, 0, stream>>>(w_qkv, wqb, 3 * E_ * E_);
    cvt_f32_f16<<<4096, 256, 0, stream>>>(w_out, wob, E_ * E_);
    gemm_qkv<<<dim3(48, 16), 256, 0, stream>>>(xb, wqb, b_qkv, Qm, Km, VTm);
    attn<<<512, 256, 0, stream>>>(Qm, Km, VTm, Om);
    gemm_out<<<dim3(16, 16), 256, 0, stream>>>(Om, wob, b_out, out);
}

// Round 3
// 339.707 us; speedup vs baseline: 1.0355x; 1.0355x over previous
//
#include <hip/hip_runtime.h>
#include <math.h>

#define S_ 2048
#define E_ 2048
#define H_ 16
#define D_ 128

typedef _Float16 f16;
typedef _Float16 f16x8 __attribute__((ext_vector_type(8)));
typedef _Float16 f16x4 __attribute__((ext_vector_type(4)));
typedef float f32x4 __attribute__((ext_vector_type(4)));

// async global->LDS, 16B per lane. LDS dest must be wave-uniform base + lane*16.
// Used ONLY in the m97-pattern GEMMs (issue -> barrier -> consume, adjacent).
#define GLDS(g, l)                                                            \
    __builtin_amdgcn_global_load_lds(                                         \
        (const __attribute__((address_space(1))) void*)(g),                   \
        (__attribute__((address_space(3))) void*)(l), 16, 0, 0)

// ---------------------------------------------------------------- convert
__global__ __launch_bounds__(256) void cvt_f32_f16(const float* __restrict__ in,
                                                   f16* __restrict__ out, int n) {
    int i = (blockIdx.x * 256 + threadIdx.x) * 4;
    if (i + 3 < n) {
        float4 v = *(const float4*)(in + i);
        f16x4 o;
        o[0] = (f16)v.x; o[1] = (f16)v.y; o[2] = (f16)v.z; o[3] = (f16)v.w;
        *(f16x4*)(out + i) = o;
    }
}

// ---------------------------------------------------------------- QKV GEMM (m97 structure)
// C[m][n] = sum_k A[m][k]*B[n][k] + bias[n]; scatters q (pre-scaled by 1/sqrt(D)),
// k into [H][S][D], v transposed into [H][D][S].
__global__ __launch_bounds__(256) void gemm_qkv(const f16* __restrict__ A,
                                                const f16* __restrict__ B,
                                                const float* __restrict__ bias,
                                                f16* __restrict__ Qm,
                                                f16* __restrict__ Km,
                                                f16* __restrict__ VTm) {
    __shared__ __align__(16) f16 As[128 * 32];   // unpadded: required by global_load_lds
    __shared__ __align__(16) f16 Bs[128 * 32];
    const int tid  = threadIdx.x;
    const int lane = tid & 63, wave = tid >> 6;
    const int lm = lane & 15, quad = lane >> 4;
    const int wm = wave >> 1, wn = wave & 1;
    const int tn0 = blockIdx.x * 128;
    const int tm0 = blockIdx.y * 128;

    const int srow = tid >> 2, scol = (tid & 3) * 8;
    const f16* Ag0 = A + (size_t)(tm0 + srow) * E_ + scol;
    const f16* Ag1 = Ag0 + (size_t)64 * E_;
    const f16* Bg0 = B + (size_t)(tn0 + srow) * E_ + scol;
    const f16* Bg1 = Bg0 + (size_t)64 * E_;
    f16* Al0 = &As[tid * 8];
    f16* Al1 = &As[(256 + tid) * 8];
    f16* Bl0 = &Bs[tid * 8];
    f16* Bl1 = &Bs[(256 + tid) * 8];

    const f32x4 vzero = {0.f, 0.f, 0.f, 0.f};
    f32x4 acc[4][4];
#pragma unroll
    for (int i = 0; i < 4; i++)
#pragma unroll
        for (int j = 0; j < 4; j++) acc[i][j] = vzero;

    for (int k0 = 0; k0 < E_; k0 += 32) {
        __syncthreads();
        GLDS(Ag0 + k0, Al0); GLDS(Ag1 + k0, Al1);
        GLDS(Bg0 + k0, Bl0); GLDS(Bg1 + k0, Bl1);
        __syncthreads();
        f16x8 af[4], bfr[4];
#pragma unroll
        for (int i = 0; i < 4; i++)
            af[i] = *(const f16x8*)&As[(wm * 64 + i * 16 + lm) * 32 + quad * 8];
#pragma unroll
        for (int j = 0; j < 4; j++)
            bfr[j] = *(const f16x8*)&Bs[(wn * 64 + j * 16 + lm) * 32 + quad * 8];
#pragma unroll
        for (int i = 0; i < 4; i++)
#pragma unroll
            for (int j = 0; j < 4; j++)
                acc[i][j] = __builtin_amdgcn_mfma_f32_16x16x32_f16(af[i], bfr[j],
                                                                   acc[i][j], 0, 0, 0);
    }

    const float qscale = 0.08838834764831845f;  // 1/sqrt(128), prefolded into Q
#pragma unroll
    for (int i = 0; i < 4; i++) {
#pragma unroll
        for (int j = 0; j < 4; j++) {
            const int n = tn0 + wn * 64 + j * 16 + lm;
            const int which = n >> 11;
            const int h = (n >> 7) & 15;
            const int d = n & 127;
            const float bv = bias[n];
#pragma unroll
            for (int r = 0; r < 4; r++) {
                const int m = tm0 + wm * 64 + i * 16 + quad * 4 + r;
                float fv = acc[i][j][r] + bv;
                if (which == 0)      Qm[((size_t)h * S_ + m) * D_ + d] = (f16)(fv * qscale);
                else if (which == 1) Km[((size_t)h * S_ + m) * D_ + d] = (f16)fv;
                else                 VTm[((size_t)h * D_ + d) * S_ + m] = (f16)fv;
            }
        }
    }
}

// ---------------------------------------------------------------- attention
// S^T = K*Q^T orientation (scalar softmax state per lane); O^T = V^T * P^T.
// Register-staged double buffer: plain global loads for tile t+1 issued after
// the ds_writes of tile t (no LDS-DMA across barriers -> no replay race).
// LDS XOR-swizzled: global reads linear, swizzle in the ds_write index.
// Complementary pairing (31-p, p): every block exactly 33 kv-iters.
__global__ __launch_bounds__(256, 1) void attn(const f16* __restrict__ Qm,
                                               const f16* __restrict__ Km,
                                               const f16* __restrict__ VTm,
                                               f16* __restrict__ Om) {
    __shared__ __align__(16) f16 Ks[64 * 128];    // [key][d-chunk swizzled]
    __shared__ __align__(16) f16 VTs[128 * 64];   // [d][key-chunk swizzled]
    __shared__ __align__(16) f16 Ps[4][16 * 72];  // per-wave P [qrow][key], pad 72

    const int tid  = threadIdx.x;
    const int lane = tid & 63, wave = tid >> 6;
    const int lm = lane & 15, quad = lane >> 4;
    const int h = blockIdx.x & 15;
    const int p = blockIdx.x >> 4;
    const int tA = 31 - p, tB = p;
    const int nIter = 33;

    const f16* KmH  = Km  + (size_t)h * S_ * D_;
    const f16* VTmH = VTm + (size_t)h * D_ * S_;
    const f16* QmH  = Qm  + (size_t)h * S_ * D_;

    // staging assignment: 4 Ks chunks + 4 VTs chunks of 16B per thread.
    // global offsets linear (coalesced); LDS offsets XOR-swizzled.
    int kg[4], kl[4], vg[4], vl[4];
#pragma unroll
    for (int rr = 0; rr < 4; rr++) {
        int c = rr * 256 + tid;
        int key = c >> 4, dc = c & 15;
        kg[rr] = key * 128 + dc * 8;
        kl[rr] = key * 128 + ((dc & 8) | ((dc & 7) ^ (key & 7))) * 8;
        int d = c >> 3, sc = c & 7;
        vg[rr] = d * 2048 + sc * 8;
        vl[rr] = d * 64 + (sc ^ (d & 7)) * 8;
    }

    const f32x4 vzero = {0.f, 0.f, 0.f, 0.f};
    f32x4 o[8];
#pragma unroll
    for (int f = 0; f < 8; f++) o[f] = vzero;
    float mi = -INFINITY, li = 0.f;

    int q0c = tA * 64 + wave * 16;                 // this wave's 16-row chunk
    f16x8 qf[4];
#pragma unroll
    for (int kc = 0; kc < 4; kc++)
        qf[kc] = *(const f16x8*)(QmH + (size_t)(q0c + lm) * D_ + kc * 32 + quad * 8);

    // prefetch tile 0 into registers
    float4 kreg[4], vreg[4];
#pragma unroll
    for (int rr = 0; rr < 4; rr++) {
        kreg[rr] = *(const float4*)(KmH + kg[rr]);
        vreg[rr] = *(const float4*)(VTmH + vg[rr]);
    }

    for (int i = 0; i < nIter; i++) {
        const bool pB = i > tA;
        const int t = pB ? i - tA - 1 : i;
        const int tmax = pB ? tB : tA;
        const int k0 = t * 64;

        __syncthreads();   // all waves done READING LDS from previous iter
#pragma unroll
        for (int rr = 0; rr < 4; rr++) {
            *(float4*)&Ks[kl[rr]] = kreg[rr];
            *(float4*)&VTs[vl[rr]] = vreg[rr];
        }
        if (i + 1 < nIter) {   // prefetch next tile; latency hides behind compute
            const int nt = (i + 1 > tA) ? (i - tA) : (i + 1);
#pragma unroll
            for (int rr = 0; rr < 4; rr++) {
                kreg[rr] = *(const float4*)(KmH + (size_t)nt * 8192 + kg[rr]);
                vreg[rr] = *(const float4*)(VTmH + nt * 64 + vg[rr]);
            }
        }
        __syncthreads();   // ds_writes visible

        // ---- S^T = K * Q^T : C[m=key][n=qrow]
        f32x4 sfr[4];
#pragma unroll
        for (int j = 0; j < 4; j++) {
            f32x4 a = vzero;
#pragma unroll
            for (int kc = 0; kc < 4; kc++) {
                int dc = kc * 4 + quad;
                int sc = (dc & 8) | ((dc & 7) ^ (lm & 7));
                f16x8 kf = *(const f16x8*)&Ks[(j * 16 + lm) * 128 + sc * 8];
                a = __builtin_amdgcn_mfma_f32_16x16x32_f16(kf, qf[kc], a, 0, 0, 0);
            }
            sfr[j] = a;
        }

        // ---- online softmax (qrow = q0c+lm; 16 key-scores per lane)
        const bool masked = (t == tmax);
        const int qrow = q0c + lm;
        float sv[4][4];
        float vmax = -3e38f;
#pragma unroll
        for (int j = 0; j < 4; j++)
#pragma unroll
            for (int r = 0; r < 4; r++) {
                float x = sfr[j][r];
                if (masked) {
                    int key = k0 + j * 16 + quad * 4 + r;
                    if (key > qrow) x = -1e30f;
                }
                sv[j][r] = x;
                vmax = fmaxf(vmax, x);
            }
        vmax = fmaxf(vmax, __shfl_xor(vmax, 16));
        vmax = fmaxf(vmax, __shfl_xor(vmax, 32));
        const float mn = fmaxf(mi, vmax);
        const float alpha = __expf(mi - mn);
        mi = mn;
        float rsum = 0.f;
#pragma unroll
        for (int j = 0; j < 4; j++) {
            f16x4 pk;
#pragma unroll
            for (int r = 0; r < 4; r++) {
                float pv = __expf(sv[j][r] - mn);
                rsum += pv;
                pk[r] = (f16)pv;
            }
            *(f16x4*)&Ps[wave][lm * 72 + j * 16 + quad * 4] = pk;
        }
        rsum += __shfl_xor(rsum, 16);
        rsum += __shfl_xor(rsum, 32);
        li = li * alpha + rsum;
#pragma unroll
        for (int f = 0; f < 8; f++) {
            o[f][0] *= alpha; o[f][1] *= alpha; o[f][2] *= alpha; o[f][3] *= alpha;
        }

        // ---- O^T += V^T * P^T  (P read back same-wave: in-order LDS, no barrier)
        f16x8 pb[2];
#pragma unroll
        for (int kc = 0; kc < 2; kc++)
            pb[kc] = *(const f16x8*)&Ps[wave][lm * 72 + kc * 32 + quad * 8];
#pragma unroll
        for (int f = 0; f < 8; f++) {
#pragma unroll
            for (int kc = 0; kc < 2; kc++) {
                int sc = (kc * 4 + quad) ^ (lm & 7);
                f16x8 vf = *(const f16x8*)&VTs[(f * 16 + lm) * 64 + sc * 8];
                o[f] = __builtin_amdgcn_mfma_f32_16x16x32_f16(vf, pb[kc], o[f], 0, 0, 0);
            }
        }

        if (i == tA) {  // phase A done: write O, reinit for light tile
            const float inv = 1.f / li;
#pragma unroll
            for (int f = 0; f < 8; f++) {
                f16x4 ov;
#pragma unroll
                for (int r = 0; r < 4; r++) ov[r] = (f16)(o[f][r] * inv);
                *(f16x4*)(Om + (size_t)(q0c + lm) * E_ + h * 128 + f * 16 + quad * 4) = ov;
                o[f] = vzero;
            }
            mi = -INFINITY; li = 0.f;
            q0c = tB * 64 + wave * 16;
#pragma unroll
            for (int kc = 0; kc < 4; kc++)
                qf[kc] = *(const f16x8*)(QmH + (size_t)(q0c + lm) * D_ + kc * 32 + quad * 8);
        }
    }

    const float inv = 1.f / li;
#pragma unroll
    for (int f = 0; f < 8; f++) {
        f16x4 ov;
#pragma unroll
        for (int r = 0; r < 4; r++) ov[r] = (f16)(o[f][r] * inv);
        *(f16x4*)(Om + (size_t)(q0c + lm) * E_ + h * 128 + f * 16 + quad * 4) = ov;
    }
}

// ---------------------------------------------------------------- out GEMM (m97 structure)
__global__ __launch_bounds__(256) void gemm_out(const f16* __restrict__ A,
                                                const f16* __restrict__ B,
                                                const float* __restrict__ bias,
                                                float* __restrict__ Cout) {
    __shared__ __align__(16) f16 As[128 * 32];
    __shared__ __align__(16) f16 Bs[128 * 32];
    const int tid  = threadIdx.x;
    const int lane = tid & 63, wave = tid >> 6;
    const int lm = lane & 15, quad = lane >> 4;
    const int wm = wave >> 1, wn = wave & 1;
    const int tn0 = blockIdx.x * 128;
    const int tm0 = blockIdx.y * 128;

    const int srow = tid >> 2, scol = (tid & 3) * 8;
    const f16* Ag0 = A + (size_t)(tm0 + srow) * E_ + scol;
    const f16* Ag1 = Ag0 + (size_t)64 * E_;
    const f16* Bg0 = B + (size_t)(tn0 + srow) * E_ + scol;
    const f16* Bg1 = Bg0 + (size_t)64 * E_;
    f16* Al0 = &As[tid * 8];
    f16* Al1 = &As[(256 + tid) * 8];
    f16* Bl0 = &Bs[tid * 8];
    f16* Bl1 = &Bs[(256 + tid) * 8];

    const f32x4 vzero = {0.f, 0.f, 0.f, 0.f};
    f32x4 acc[4][4];
#pragma unroll
    for (int i = 0; i < 4; i++)
#pragma unroll
        for (int j = 0; j < 4; j++) acc[i][j] = vzero;

    for (int k0 = 0; k0 < E_; k0 += 32) {
        __syncthreads();
        GLDS(Ag0 + k0, Al0); GLDS(Ag1 + k0, Al1);
        GLDS(Bg0 + k0, Bl0); GLDS(Bg1 + k0, Bl1);
        __syncthreads();
        f16x8 af[4], bfr[4];
#pragma unroll
        for (int i = 0; i < 4; i++)
            af[i] = *(const f16x8*)&As[(wm * 64 + i * 16 + lm) * 32 + quad * 8];
#pragma unroll
        for (int j = 0; j < 4; j++)
            bfr[j] = *(const f16x8*)&Bs[(wn * 64 + j * 16 + lm) * 32 + quad * 8];
#pragma unroll
        for (int i = 0; i < 4; i++)
#pragma unroll
            for (int j = 0; j < 4; j++)
                acc[i][j] = __builtin_amdgcn_mfma_f32_16x16x32_f16(af[i], bfr[j],
                                                                   acc[i][j], 0, 0, 0);
    }

#pragma unroll
    for (int i = 0; i < 4; i++) {
#pragma unroll
        for (int j = 0; j < 4; j++) {
            const int n = tn0 + wn * 64 + j * 16 + lm;
            const float bv = bias[n];
#pragma unroll
            for (int r = 0; r < 4; r++) {
                const int m = tm0 + wm * 64 + i * 16 + quad * 4 + r;
                Cout[(size_t)m * E_ + n] = acc[i][j][r] + bv;
            }
        }
    }
}

// ---------------------------------------------------------------- launch
extern "C" void kernel_launch(void* const* d_in, const int* in_sizes, int n_in,
                              void* d_out, int out_size, void* d_ws, size_t ws_size,
                              hipStream_t stream) {
    const float* x     = (const float*)d_in[0];
    const float* w_qkv = (const float*)d_in[1];
    const float* b_qkv = (const float*)d_in[2];
    const float* w_out = (const float*)d_in[3];
    const float* b_out = (const float*)d_in[4];
    float* out = (float*)d_out;

    char* ws = (char*)d_ws;
    f16* xb  = (f16*)ws; ws += (size_t)S_ * E_ * 2;
    f16* wqb = (f16*)ws; ws += (size_t)3 * E_ * E_ * 2;
    f16* wob = (f16*)ws; ws += (size_t)E_ * E_ * 2;
    f16* Qm  = (f16*)ws; ws += (size_t)H_ * S_ * D_ * 2;
    f16* Km  = (f16*)ws; ws += (size_t)H_ * S_ * D_ * 2;
    f16* VTm = (f16*)ws; ws += (size_t)H_ * D_ * S_ * 2;
    f16* Om  = (f16*)ws; ws += (size_t)S_ * E_ * 2;

    cvt_f32_f16<<<4096, 256, 0, stream>>>(x, xb, S_ * E_);
    cvt_f32_f16<<<12288, 256, 0, stream>>>(w_qkv, wqb, 3 * E_ * E_);
    cvt_f32_f16<<<4096, 256, 0, stream>>>(w_out, wob, E_ * E_);
    gemm_qkv<<<dim3(48, 16), 256, 0, stream>>>(xb, wqb, b_qkv, Qm, Km, VTm);
    attn<<<256, 256, 0, stream>>>(Qm, Km, VTm, Om);
    gemm_out<<<dim3(16, 16), 256, 0, stream>>>(Om, wob, b_out, out);
}

// Round 4
// 330.040 us; speedup vs baseline: 1.0658x; 1.0293x over previous
//
#include <hip/hip_runtime.h>
#include <math.h>

#define S_ 2048
#define E_ 2048
#define H_ 16
#define D_ 128

typedef _Float16 f16;
typedef _Float16 f16x8 __attribute__((ext_vector_type(8)));
typedef _Float16 f16x4 __attribute__((ext_vector_type(4)));
typedef float f32x4 __attribute__((ext_vector_type(4)));

// async global->LDS, 16B per lane. LDS dest must be wave-uniform base + lane*16.
// Used ONLY in the m97-pattern GEMMs (issue -> barrier -> consume, adjacent).
#define GLDS(g, l)                                                            \
    __builtin_amdgcn_global_load_lds(                                         \
        (const __attribute__((address_space(1))) void*)(g),                   \
        (__attribute__((address_space(3))) void*)(l), 16, 0, 0)

// ---------------------------------------------------------------- convert
__global__ __launch_bounds__(256) void cvt_f32_f16(const float* __restrict__ in,
                                                   f16* __restrict__ out, int n) {
    int i = (blockIdx.x * 256 + threadIdx.x) * 4;
    if (i + 3 < n) {
        float4 v = *(const float4*)(in + i);
        f16x4 o;
        o[0] = (f16)v.x; o[1] = (f16)v.y; o[2] = (f16)v.z; o[3] = (f16)v.w;
        *(f16x4*)(out + i) = o;
    }
}

// ---------------------------------------------------------------- QKV GEMM (m97 structure)
// C[m][n] = sum_k A[m][k]*B[n][k] + bias[n]; scatters q (pre-scaled by 1/sqrt(D)),
// k into [H][S][D], v transposed into [H][D][S].
__global__ __launch_bounds__(256) void gemm_qkv(const f16* __restrict__ A,
                                                const f16* __restrict__ B,
                                                const float* __restrict__ bias,
                                                f16* __restrict__ Qm,
                                                f16* __restrict__ Km,
                                                f16* __restrict__ VTm) {
    __shared__ __align__(16) f16 As[128 * 32];   // unpadded: required by global_load_lds
    __shared__ __align__(16) f16 Bs[128 * 32];
    const int tid  = threadIdx.x;
    const int lane = tid & 63, wave = tid >> 6;
    const int lm = lane & 15, quad = lane >> 4;
    const int wm = wave >> 1, wn = wave & 1;
    const int tn0 = blockIdx.x * 128;
    const int tm0 = blockIdx.y * 128;

    const int srow = tid >> 2, scol = (tid & 3) * 8;
    const f16* Ag0 = A + (size_t)(tm0 + srow) * E_ + scol;
    const f16* Ag1 = Ag0 + (size_t)64 * E_;
    const f16* Bg0 = B + (size_t)(tn0 + srow) * E_ + scol;
    const f16* Bg1 = Bg0 + (size_t)64 * E_;
    f16* Al0 = &As[tid * 8];
    f16* Al1 = &As[(256 + tid) * 8];
    f16* Bl0 = &Bs[tid * 8];
    f16* Bl1 = &Bs[(256 + tid) * 8];

    const f32x4 vzero = {0.f, 0.f, 0.f, 0.f};
    f32x4 acc[4][4];
#pragma unroll
    for (int i = 0; i < 4; i++)
#pragma unroll
        for (int j = 0; j < 4; j++) acc[i][j] = vzero;

    for (int k0 = 0; k0 < E_; k0 += 32) {
        __syncthreads();
        GLDS(Ag0 + k0, Al0); GLDS(Ag1 + k0, Al1);
        GLDS(Bg0 + k0, Bl0); GLDS(Bg1 + k0, Bl1);
        __syncthreads();
        f16x8 af[4], bfr[4];
#pragma unroll
        for (int i = 0; i < 4; i++)
            af[i] = *(const f16x8*)&As[(wm * 64 + i * 16 + lm) * 32 + quad * 8];
#pragma unroll
        for (int j = 0; j < 4; j++)
            bfr[j] = *(const f16x8*)&Bs[(wn * 64 + j * 16 + lm) * 32 + quad * 8];
#pragma unroll
        for (int i = 0; i < 4; i++)
#pragma unroll
            for (int j = 0; j < 4; j++)
                acc[i][j] = __builtin_amdgcn_mfma_f32_16x16x32_f16(af[i], bfr[j],
                                                                   acc[i][j], 0, 0, 0);
    }

    const float qscale = 0.08838834764831845f;  // 1/sqrt(128), prefolded into Q
#pragma unroll
    for (int i = 0; i < 4; i++) {
#pragma unroll
        for (int j = 0; j < 4; j++) {
            const int n = tn0 + wn * 64 + j * 16 + lm;
            const int which = n >> 11;
            const int h = (n >> 7) & 15;
            const int d = n & 127;
            const float bv = bias[n];
#pragma unroll
            for (int r = 0; r < 4; r++) {
                const int m = tm0 + wm * 64 + i * 16 + quad * 4 + r;
                float fv = acc[i][j][r] + bv;
                if (which == 0)      Qm[((size_t)h * S_ + m) * D_ + d] = (f16)(fv * qscale);
                else if (which == 1) Km[((size_t)h * S_ + m) * D_ + d] = (f16)fv;
                else                 VTm[((size_t)h * D_ + d) * S_ + m] = (f16)fv;
            }
        }
    }
}

// ---------------------------------------------------------------- attention
// S^T = K*Q^T orientation (scalar softmax state per lane); O^T = V^T * P^T.
// Register-staged double buffer; LDS XOR-swizzled.
// Grid 512 = 32 q-tiles x 16 heads -> 2 blocks/CU (LDS 41KB, VGPR 84).
// Stripe mapping pairs heavy+light q-tiles on the same CU under round-robin
// placement: CU c gets qt=31-s and qt=s-16 -> flat 34 kv-iters per CU.
__global__ __launch_bounds__(256, 2) void attn(const f16* __restrict__ Qm,
                                               const f16* __restrict__ Km,
                                               const f16* __restrict__ VTm,
                                               f16* __restrict__ Om) {
    __shared__ __align__(16) f16 Ks[64 * 128];    // [key][d-chunk swizzled]
    __shared__ __align__(16) f16 VTs[128 * 64];   // [d][key-chunk swizzled]
    __shared__ __align__(16) f16 Ps[4][16 * 72];  // per-wave P [qrow][key], pad 72

    const int tid  = threadIdx.x;
    const int lane = tid & 63, wave = tid >> 6;
    const int lm = lane & 15, quad = lane >> 4;
    const int bx = blockIdx.x;
    const int st = bx >> 4;                       // stripe-paired heavy/light
    const int qt = (st < 16) ? (31 - st) : (st - 16);
    const int h  = bx & 15;
    const int nIter = qt + 1;

    const f16* KmH  = Km  + (size_t)h * S_ * D_;
    const f16* VTmH = VTm + (size_t)h * D_ * S_;
    const f16* QmH  = Qm  + (size_t)h * S_ * D_;

    // staging assignment: 4 Ks chunks + 4 VTs chunks of 16B per thread.
    // global offsets linear (coalesced); LDS offsets XOR-swizzled.
    int kg[4], kl[4], vg[4], vl[4];
#pragma unroll
    for (int rr = 0; rr < 4; rr++) {
        int c = rr * 256 + tid;
        int key = c >> 4, dc = c & 15;
        kg[rr] = key * 128 + dc * 8;
        kl[rr] = key * 128 + ((dc & 8) | ((dc & 7) ^ (key & 7))) * 8;
        int d = c >> 3, sc = c & 7;
        vg[rr] = d * 2048 + sc * 8;
        vl[rr] = d * 64 + (sc ^ (d & 7)) * 8;
    }

    const f32x4 vzero = {0.f, 0.f, 0.f, 0.f};
    f32x4 o[8];
#pragma unroll
    for (int f = 0; f < 8; f++) o[f] = vzero;
    float mi = -INFINITY, li = 0.f;

    const int q0c = qt * 64 + wave * 16;           // this wave's 16-row chunk
    f16x8 qf[4];
#pragma unroll
    for (int kc = 0; kc < 4; kc++)
        qf[kc] = *(const f16x8*)(QmH + (size_t)(q0c + lm) * D_ + kc * 32 + quad * 8);

    // prefetch tile 0 into registers
    float4 kreg[4], vreg[4];
#pragma unroll
    for (int rr = 0; rr < 4; rr++) {
        kreg[rr] = *(const float4*)(KmH + kg[rr]);
        vreg[rr] = *(const float4*)(VTmH + vg[rr]);
    }

    for (int t = 0; t < nIter; t++) {
        const int k0 = t * 64;

        __syncthreads();   // all waves done READING LDS from previous iter
#pragma unroll
        for (int rr = 0; rr < 4; rr++) {
            *(float4*)&Ks[kl[rr]] = kreg[rr];
            *(float4*)&VTs[vl[rr]] = vreg[rr];
        }
        if (t + 1 < nIter) {   // prefetch next tile; latency hides behind compute
            const int nt = t + 1;
#pragma unroll
            for (int rr = 0; rr < 4; rr++) {
                kreg[rr] = *(const float4*)(KmH + (size_t)nt * 8192 + kg[rr]);
                vreg[rr] = *(const float4*)(VTmH + nt * 64 + vg[rr]);
            }
        }
        __syncthreads();   // ds_writes visible

        // ---- S^T = K * Q^T : C[m=key][n=qrow]
        f32x4 sfr[4];
#pragma unroll
        for (int j = 0; j < 4; j++) {
            f32x4 a = vzero;
#pragma unroll
            for (int kc = 0; kc < 4; kc++) {
                int dc = kc * 4 + quad;
                int sc = (dc & 8) | ((dc & 7) ^ (lm & 7));
                f16x8 kf = *(const f16x8*)&Ks[(j * 16 + lm) * 128 + sc * 8];
                a = __builtin_amdgcn_mfma_f32_16x16x32_f16(kf, qf[kc], a, 0, 0, 0);
            }
            sfr[j] = a;
        }

        // ---- online softmax (qrow = q0c+lm; 16 key-scores per lane)
        const bool masked = (t == qt);
        const int qrow = q0c + lm;
        float sv[4][4];
        float vmax = -3e38f;
#pragma unroll
        for (int j = 0; j < 4; j++)
#pragma unroll
            for (int r = 0; r < 4; r++) {
                float x = sfr[j][r];
                if (masked) {
                    int key = k0 + j * 16 + quad * 4 + r;
                    if (key > qrow) x = -1e30f;
                }
                sv[j][r] = x;
                vmax = fmaxf(vmax, x);
            }
        vmax = fmaxf(vmax, __shfl_xor(vmax, 16));
        vmax = fmaxf(vmax, __shfl_xor(vmax, 32));
        const float mn = fmaxf(mi, vmax);
        const float alpha = __expf(mi - mn);
        mi = mn;
        float rsum = 0.f;
#pragma unroll
        for (int j = 0; j < 4; j++) {
            f16x4 pk;
#pragma unroll
            for (int r = 0; r < 4; r++) {
                float pv = __expf(sv[j][r] - mn);
                rsum += pv;
                pk[r] = (f16)pv;
            }
            *(f16x4*)&Ps[wave][lm * 72 + j * 16 + quad * 4] = pk;
        }
        rsum += __shfl_xor(rsum, 16);
        rsum += __shfl_xor(rsum, 32);
        li = li * alpha + rsum;
#pragma unroll
        for (int f = 0; f < 8; f++) {
            o[f][0] *= alpha; o[f][1] *= alpha; o[f][2] *= alpha; o[f][3] *= alpha;
        }

        // ---- O^T += V^T * P^T  (P read back same-wave: in-order LDS, no barrier)
        f16x8 pb[2];
#pragma unroll
        for (int kc = 0; kc < 2; kc++)
            pb[kc] = *(const f16x8*)&Ps[wave][lm * 72 + kc * 32 + quad * 8];
#pragma unroll
        for (int f = 0; f < 8; f++) {
#pragma unroll
            for (int kc = 0; kc < 2; kc++) {
                int sc = (kc * 4 + quad) ^ (lm & 7);
                f16x8 vf = *(const f16x8*)&VTs[(f * 16 + lm) * 64 + sc * 8];
                o[f] = __builtin_amdgcn_mfma_f32_16x16x32_f16(vf, pb[kc], o[f], 0, 0, 0);
            }
        }
    }

    const float inv = 1.f / li;
#pragma unroll
    for (int f = 0; f < 8; f++) {
        f16x4 ov;
#pragma unroll
        for (int r = 0; r < 4; r++) ov[r] = (f16)(o[f][r] * inv);
        *(f16x4*)(Om + (size_t)(q0c + lm) * E_ + h * 128 + f * 16 + quad * 4) = ov;
    }
}

// ---------------------------------------------------------------- out GEMM (m97 structure)
__global__ __launch_bounds__(256) void gemm_out(const f16* __restrict__ A,
                                                const f16* __restrict__ B,
                                                const float* __restrict__ bias,
                                                float* __restrict__ Cout) {
    __shared__ __align__(16) f16 As[128 * 32];
    __shared__ __align__(16) f16 Bs[128 * 32];
    const int tid  = threadIdx.x;
    const int lane = tid & 63, wave = tid >> 6;
    const int lm = lane & 15, quad = lane >> 4;
    const int wm = wave >> 1, wn = wave & 1;
    const int tn0 = blockIdx.x * 128;
    const int tm0 = blockIdx.y * 128;

    const int srow = tid >> 2, scol = (tid & 3) * 8;
    const f16* Ag0 = A + (size_t)(tm0 + srow) * E_ + scol;
    const f16* Ag1 = Ag0 + (size_t)64 * E_;
    const f16* Bg0 = B + (size_t)(tn0 + srow) * E_ + scol;
    const f16* Bg1 = Bg0 + (size_t)64 * E_;
    f16* Al0 = &As[tid * 8];
    f16* Al1 = &As[(256 + tid) * 8];
    f16* Bl0 = &Bs[tid * 8];
    f16* Bl1 = &Bs[(256 + tid) * 8];

    const f32x4 vzero = {0.f, 0.f, 0.f, 0.f};
    f32x4 acc[4][4];
#pragma unroll
    for (int i = 0; i < 4; i++)
#pragma unroll
        for (int j = 0; j < 4; j++) acc[i][j] = vzero;

    for (int k0 = 0; k0 < E_; k0 += 32) {
        __syncthreads();
        GLDS(Ag0 + k0, Al0); GLDS(Ag1 + k0, Al1);
        GLDS(Bg0 + k0, Bl0); GLDS(Bg1 + k0, Bl1);
        __syncthreads();
        f16x8 af[4], bfr[4];
#pragma unroll
        for (int i = 0; i < 4; i++)
            af[i] = *(const f16x8*)&As[(wm * 64 + i * 16 + lm) * 32 + quad * 8];
#pragma unroll
        for (int j = 0; j < 4; j++)
            bfr[j] = *(const f16x8*)&Bs[(wn * 64 + j * 16 + lm) * 32 + quad * 8];
#pragma unroll
        for (int i = 0; i < 4; i++)
#pragma unroll
            for (int j = 0; j < 4; j++)
                acc[i][j] = __builtin_amdgcn_mfma_f32_16x16x32_f16(af[i], bfr[j],
                                                                   acc[i][j], 0, 0, 0);
    }

#pragma unroll
    for (int i = 0; i < 4; i++) {
#pragma unroll
        for (int j = 0; j < 4; j++) {
            const int n = tn0 + wn * 64 + j * 16 + lm;
            const float bv = bias[n];
#pragma unroll
            for (int r = 0; r < 4; r++) {
                const int m = tm0 + wm * 64 + i * 16 + quad * 4 + r;
                Cout[(size_t)m * E_ + n] = acc[i][j][r] + bv;
            }
        }
    }
}

// ---------------------------------------------------------------- launch
extern "C" void kernel_launch(void* const* d_in, const int* in_sizes, int n_in,
                              void* d_out, int out_size, void* d_ws, size_t ws_size,
                              hipStream_t stream) {
    const float* x     = (const float*)d_in[0];
    const float* w_qkv = (const float*)d_in[1];
    const float* b_qkv = (const float*)d_in[2];
    const float* w_out = (const float*)d_in[3];
    const float* b_out = (const float*)d_in[4];
    float* out = (float*)d_out;

    char* ws = (char*)d_ws;
    f16* xb  = (f16*)ws; ws += (size_t)S_ * E_ * 2;
    f16* wqb = (f16*)ws; ws += (size_t)3 * E_ * E_ * 2;
    f16* wob = (f16*)ws; ws += (size_t)E_ * E_ * 2;
    f16* Qm  = (f16*)ws; ws += (size_t)H_ * S_ * D_ * 2;
    f16* Km  = (f16*)ws; ws += (size_t)H_ * S_ * D_ * 2;
    f16* VTm = (f16*)ws; ws += (size_t)H_ * D_ * S_ * 2;
    f16* Om  = (f16*)ws; ws += (size_t)S_ * E_ * 2;

    cvt_f32_f16<<<4096, 256, 0, stream>>>(x, xb, S_ * E_);
    cvt_f32_f16<<<12288, 256, 0, stream>>>(w_qkv, wqb, 3 * E_ * E_);
    cvt_f32_f16<<<4096, 256, 0, stream>>>(w_out, wob, E_ * E_);
    gemm_qkv<<<dim3(48, 16), 256, 0, stream>>>(xb, wqb, b_qkv, Qm, Km, VTm);
    attn<<<512, 256, 0, stream>>>(Qm, Km, VTm, Om);
    gemm_out<<<dim3(16, 16), 256, 0, stream>>>(Om, wob, b_out, out);
}